// Round 10
// baseline (62.365 us; speedup 1.0000x reference)
//
#include <hip/hip_runtime.h>
#include <math.h>

// Analytic collapse (verified R1-R9, absmax 3.9e-3):
//   t = tanh(W1 @ x_n); v = tanh(W2 @ t); z = Wout . v
//   a = sum_h sob[h]*sin(2*pi*soa[h]*z/7);  out = sign(a)*4*z*e^|a|/(4e^|a|+5)
//
// R10: identical fp32-emulated MFMA arithmetic (bf16 3-level split, 6 products
// per accumulator, same order -> bit-identical). Ratio change:
//   - 64 rows/wave (2 row-groups) x all 128 outputs: 48 MFMA per K16-step per
//     wave; 1 wave/SIMD (grid 256, 4-wave blocks, 1 block/CU, 88 KB LDS).
//   - LDS A-read traffic per CU drops 4x (4 waves share each 12 KB batch).
//   - single-wave/SIMD floor = MFMA-issue + VALU-issue ~ 21 us, no reliance
//     on cross-wave phase overlap.
//   - tf h/m planes in regs; l-plane in wave-private LDS [s][lane] (no bank
//     conflicts); counted vmcnt per phase (7 = 3 glds + 4 x-loads).

typedef __bf16 bf16x8 __attribute__((ext_vector_type(8)));
typedef float  f32x16 __attribute__((ext_vector_type(16)));
typedef unsigned int u32;
typedef unsigned short u16;

union FRAG { uint4 q; bf16x8 v; };

#define NROWS 65536

// ---- bf16 3-level split: x = h + m + l + O(2^-25 |x|) ----
__device__ __forceinline__ void split3(float x, u32& h, u32& m, u32& l) {
    u32 u = __float_as_uint(x);
    h = u >> 16;
    float hf = __uint_as_float(u & 0xFFFF0000u);
    float r1 = x - hf;                       // exact
    u32 u1 = __float_as_uint(r1);
    m = u1 >> 16;
    float mf = __uint_as_float(u1 & 0xFFFF0000u);
    float r2 = r1 - mf;                      // exact
    u32 u2 = __float_as_uint(r2);
    l = (u2 + 0x7FFFu + ((u2 >> 16) & 1u)) >> 16;   // RNE
}

__device__ __forceinline__ void pack2(float a, float b, u32& H, u32& M, u32& L) {
    u32 h0, m0, l0, h1, m1, l1;
    split3(a, h0, m0, l0); split3(b, h1, m1, l1);
    H = h0 | (h1 << 16); M = m0 | (m1 << 16); L = l0 | (l1 << 16);
}

__device__ __forceinline__ float fast_tanh(float x) {
    float e = __expf(2.f * x);
    return 1.f - 2.f * __builtin_amdgcn_rcpf(e + 1.f);  // inf-safe, ~4e-7 abs err
}

__device__ __forceinline__ void glds16(const uint4* g, uint4* l) {
    __builtin_amdgcn_global_load_lds(
        (const __attribute__((address_space(1))) void*)g,
        (__attribute__((address_space(3))) void*)l, 16, 0, 0);
}

// ====== pre-kernel: split W1/W2 into fragment-major bf16 planes in d_ws ======
// uint4 units: L1 frag f=g*4+ot, levels at 0/4096/8192, idx=lv*4096+f*64+lane
//              L2 frag f2=s*4+ot, at 12288+lv*2048+f2*64+lane
__global__ void presplit(const float* __restrict__ W1,
                         const float* __restrict__ W2,
                         u16* __restrict__ ws)
{
    int t = blockIdx.x * 256 + threadIdx.x;   // 0..6143
    const float* src;
    size_t dbase, lstep;
    if (t < 4096) {
        int f = t >> 6, lane = t & 63;
        int c = f >> 4, s = (f >> 2) & 3, ot = f & 3;
        int l31 = lane & 31, hi = lane >> 5;
        src   = W1 + (size_t)(32 * ot + l31) * 256 + c * 64 + s * 16 + 8 * hi;
        dbase = (size_t)(f * 64 + lane) * 8;
        lstep = 32768;
    } else {
        int t2 = t - 4096;
        int f = t2 >> 6, lane = t2 & 63;
        int s = f >> 2, ot = f & 3;
        int l31 = lane & 31, hi = lane >> 5;
        src   = W2 + (size_t)(32 * ot + l31) * 128 + s * 16 + 8 * hi;
        dbase = 98304 + (size_t)(f * 64 + lane) * 8;
        lstep = 16384;
    }
    u16 H[8], M[8], L[8];
    #pragma unroll
    for (int j = 0; j < 8; ++j) {
        u32 h, m, l;
        split3(src[j], h, m, l);
        H[j] = (u16)h; M[j] = (u16)m; L[j] = (u16)l;
    }
    #pragma unroll
    for (int j = 0; j < 8; ++j) {
        ws[dbase + j]             = H[j];
        ws[dbase + lstep + j]     = M[j];
        ws[dbase + 2 * lstep + j] = L[j];
    }
}

// ================= main kernel ==============================================
// 256 thr = 4 waves; wave w owns 64 rows (2 row-groups of 32); 256 rows/block;
// grid = 256 -> 1 block/CU, 1 wave/SIMD.
__global__ __launch_bounds__(256, 1)
void fused_mlp10(const float* __restrict__ x,
                 const u16*   __restrict__ wsp,
                 const float* __restrict__ Wout,
                 const float* __restrict__ soa,
                 const float* __restrict__ sob,
                 float* __restrict__ out)
{
    __shared__ uint4 Ab[2][768];              // 24 KB A-batch double buffer
    __shared__ uint4 tl[4096];                // 64 KB tf l-plane [w][rg][s][lane]

    const int tid  = threadIdx.x;
    const int w    = tid >> 6;                // 0..3
    const int lane = tid & 63;
    const int l31  = lane & 31;
    const int hi   = lane >> 5;
    const int n0   = blockIdx.x * 256 + 64 * w;   // wave's global row base

    const uint4*  wf    = reinterpret_cast<const uint4*>(wsp);
    const float4* xrow0 = reinterpret_cast<const float4*>(x) + (size_t)(n0 + l31) * 64;
    const float4* xrow1 = xrow0 + 32 * 64;    // rg1 rows

    // wave w stages items i = 3w..3w+2 (of 12) of K16-step g's A-batch
    auto stage = [&](int g, uint4* dst) {
        #pragma unroll
        for (int j = 0; j < 3; ++j) {
            int i  = w * 3 + j;               // 0..11
            int lv = i >> 2, ot = i & 3;
            const uint4* src = (g < 16)
                ? wf + lv * 4096 + (g * 4 + ot) * 64 + lane
                : wf + 12288 + lv * 2048 + ((g - 16) * 4 + ot) * 64 + lane;
            glds16(src, dst + i * 64);
        }
    };

    f32x16 acc[4][2];
    #pragma unroll
    for (int ot = 0; ot < 4; ++ot) {
        acc[ot][0] = (f32x16)0.f;
        acc[ot][1] = (f32x16)0.f;
    }

    auto packB = [&](const float4& a, const float4& b, FRAG& Bh, FRAG& Bm, FRAG& Bl) {
        pack2(a.x, a.y, Bh.q.x, Bm.q.x, Bl.q.x);
        pack2(a.z, a.w, Bh.q.y, Bm.q.y, Bl.q.y);
        pack2(b.x, b.y, Bh.q.z, Bm.q.z, Bl.q.z);
        pack2(b.z, b.w, Bh.q.w, Bm.q.w, Bl.q.w);
    };

    // 48-MFMA cluster: 4 ot x 2 rg x 6 products (per-acc order preserved)
    auto cluster = [&](const uint4* Ac, f32x16 (*A)[2],
                       const FRAG& B0h, const FRAG& B0m, const FRAG& B0l,
                       const FRAG& B1h, const FRAG& B1m, const FRAG& B1l) {
        __builtin_amdgcn_s_setprio(1);
        #pragma unroll
        for (int ot = 0; ot < 4; ++ot) {
            FRAG Ah, Am, Al;
            Ah.q = Ac[ot * 64 + lane];
            Am.q = Ac[(4 + ot) * 64 + lane];
            Al.q = Ac[(8 + ot) * 64 + lane];
            A[ot][0] = __builtin_amdgcn_mfma_f32_32x32x16_bf16(Ah.v, B0h.v, A[ot][0], 0,0,0);
            A[ot][1] = __builtin_amdgcn_mfma_f32_32x32x16_bf16(Ah.v, B1h.v, A[ot][1], 0,0,0);
            A[ot][0] = __builtin_amdgcn_mfma_f32_32x32x16_bf16(Ah.v, B0m.v, A[ot][0], 0,0,0);
            A[ot][1] = __builtin_amdgcn_mfma_f32_32x32x16_bf16(Ah.v, B1m.v, A[ot][1], 0,0,0);
            A[ot][0] = __builtin_amdgcn_mfma_f32_32x32x16_bf16(Am.v, B0h.v, A[ot][0], 0,0,0);
            A[ot][1] = __builtin_amdgcn_mfma_f32_32x32x16_bf16(Am.v, B1h.v, A[ot][1], 0,0,0);
            A[ot][0] = __builtin_amdgcn_mfma_f32_32x32x16_bf16(Am.v, B0m.v, A[ot][0], 0,0,0);
            A[ot][1] = __builtin_amdgcn_mfma_f32_32x32x16_bf16(Am.v, B1m.v, A[ot][1], 0,0,0);
            A[ot][0] = __builtin_amdgcn_mfma_f32_32x32x16_bf16(Ah.v, B0l.v, A[ot][0], 0,0,0);
            A[ot][1] = __builtin_amdgcn_mfma_f32_32x32x16_bf16(Ah.v, B1l.v, A[ot][1], 0,0,0);
            A[ot][0] = __builtin_amdgcn_mfma_f32_32x32x16_bf16(Al.v, B0h.v, A[ot][0], 0,0,0);
            A[ot][1] = __builtin_amdgcn_mfma_f32_32x32x16_bf16(Al.v, B1h.v, A[ot][1], 0,0,0);
        }
        __builtin_amdgcn_s_setprio(0);
    };

    // ---- prologue: A(0) -> buf0; x(0) for both rg ----
    stage(0, Ab[0]);
    float4 xA0 = xrow0[hi * 2], xA1 = xrow0[hi * 2 + 1];
    float4 xA2 = xrow1[hi * 2], xA3 = xrow1[hi * 2 + 1];

    // =================== layer 1: 16 phases (2 per iteration) ================
    #pragma unroll 1
    for (int gp = 0; gp < 8; ++gp) {
        // ---- phase g = 2gp (reads buf0) ----
        asm volatile("s_barrier" ::: "memory");
        stage(2 * gp + 1, Ab[1]);
        float4 xB0, xB1, xB2, xB3;
        {
            int gn = 2 * gp + 1;
            xB0 = xrow0[gn * 4 + hi * 2];
            xB1 = xrow0[gn * 4 + hi * 2 + 1];
            xB2 = xrow1[gn * 4 + hi * 2];
            xB3 = xrow1[gn * 4 + hi * 2 + 1];
        }
        asm volatile("s_waitcnt vmcnt(7)" ::: "memory");   // A(2gp)+x(2gp) landed
        __builtin_amdgcn_sched_barrier(0);
        {
            FRAG B0h, B0m, B0l, B1h, B1m, B1l;
            packB(xA0, xA1, B0h, B0m, B0l);
            packB(xA2, xA3, B1h, B1m, B1l);
            cluster(Ab[0], acc, B0h, B0m, B0l, B1h, B1m, B1l);
        }

        // ---- phase g = 2gp+1 (reads buf1) ----
        asm volatile("s_barrier" ::: "memory");
        stage(2 * gp + 2, Ab[0]);                          // gp=7 -> stage(16)
        if (gp < 7) {
            int gn = 2 * gp + 2;
            xA0 = xrow0[gn * 4 + hi * 2];
            xA1 = xrow0[gn * 4 + hi * 2 + 1];
            xA2 = xrow1[gn * 4 + hi * 2];
            xA3 = xrow1[gn * 4 + hi * 2 + 1];
            asm volatile("s_waitcnt vmcnt(7)" ::: "memory");
        } else {
            asm volatile("s_waitcnt vmcnt(3)" ::: "memory"); // only 3 glds issued
        }
        __builtin_amdgcn_sched_barrier(0);
        {
            FRAG B0h, B0m, B0l, B1h, B1m, B1l;
            packB(xB0, xB1, B0h, B0m, B0l);
            packB(xB2, xB3, B1h, B1m, B1l);
            cluster(Ab[1], acc, B0h, B0m, B0l, B1h, B1m, B1l);
        }
    }

    // ====== t = tanh(D1); build layer-2 B-frags (h,m regs; l -> LDS) ======
    // (batch 16 DMA in flight; tf build hides its latency)
    FRAG tfh[8][2], tfm[8][2];
    #pragma unroll
    for (int ft = 0; ft < 4; ++ft) {
        #pragma unroll
        for (int sub = 0; sub < 2; ++sub) {
            int s = 2 * ft + sub;
            #pragma unroll
            for (int rg = 0; rg < 2; ++rg) {
                float tv[8];
                u32 th[8], tm[8], tlv[8];
                #pragma unroll
                for (int j = 0; j < 8; ++j) {
                    tv[j] = fast_tanh(acc[ft][rg][8 * sub + j]);
                    split3(tv[j], th[j], tm[j], tlv[j]);
                }
                #pragma unroll
                for (int lv = 0; lv < 3; ++lv) {
                    const u32* t_ = (lv == 0) ? th : (lv == 1) ? tm : tlv;
                    u32 P0 = t_[0] | (t_[1] << 16);
                    u32 P1 = t_[2] | (t_[3] << 16);
                    u32 Q0 = t_[4] | (t_[5] << 16);
                    u32 Q1 = t_[6] | (t_[7] << 16);
                    u32 sP0 = (u32)__shfl_xor((int)P0, 32);
                    u32 sP1 = (u32)__shfl_xor((int)P1, 32);
                    u32 sQ0 = (u32)__shfl_xor((int)Q0, 32);
                    u32 sQ1 = (u32)__shfl_xor((int)Q1, 32);
                    uint4 q;
                    q.x = hi ? sQ0 : P0;
                    q.y = hi ? sQ1 : P1;
                    q.z = hi ? Q0 : sP0;
                    q.w = hi ? Q1 : sP1;
                    if (lv == 0)      tfh[s][rg].q = q;
                    else if (lv == 1) tfm[s][rg].q = q;
                    else              tl[w * 1024 + rg * 512 + s * 64 + lane] = q;
                }
            }
        }
    }

    // =================== layer 2: 8 phases (fully unrolled) ==================
    f32x16 acc2[4][2];
    #pragma unroll
    for (int ot = 0; ot < 4; ++ot) {
        acc2[ot][0] = (f32x16)0.f;
        acc2[ot][1] = (f32x16)0.f;
    }

    #pragma unroll
    for (int s = 0; s < 8; ++s) {
        asm volatile("s_barrier" ::: "memory");
        if (s < 7) {
            stage(17 + s, Ab[(17 + s) & 1]);
            asm volatile("s_waitcnt vmcnt(3)" ::: "memory");  // A(16+s) landed
        } else {
            asm volatile("s_waitcnt vmcnt(0)" ::: "memory");  // last batch
        }
        __builtin_amdgcn_sched_barrier(0);
        FRAG B0l, B1l;
        B0l.q = tl[w * 1024 + s * 64 + lane];
        B1l.q = tl[w * 1024 + 512 + s * 64 + lane];
        cluster(Ab[(16 + s) & 1], acc2,
                tfh[s][0], tfm[s][0], B0l,
                tfh[s][1], tfm[s][1], B1l);
    }

    // ====== epilogue: v = tanh(D2); z = Wout . v ; analytic tail ======
    float zp0 = 0.f, zp1 = 0.f;
    #pragma unroll
    for (int ft = 0; ft < 4; ++ft) {
        #pragma unroll
        for (int rg4 = 0; rg4 < 4; ++rg4) {
            const float4 wo = *reinterpret_cast<const float4*>(Wout + 32 * ft + 8 * rg4 + 4 * hi);
            zp0 += fast_tanh(acc2[ft][0][4 * rg4 + 0]) * wo.x
                 + fast_tanh(acc2[ft][0][4 * rg4 + 1]) * wo.y
                 + fast_tanh(acc2[ft][0][4 * rg4 + 2]) * wo.z
                 + fast_tanh(acc2[ft][0][4 * rg4 + 3]) * wo.w;
            zp1 += fast_tanh(acc2[ft][1][4 * rg4 + 0]) * wo.x
                 + fast_tanh(acc2[ft][1][4 * rg4 + 1]) * wo.y
                 + fast_tanh(acc2[ft][1][4 * rg4 + 2]) * wo.z
                 + fast_tanh(acc2[ft][1][4 * rg4 + 3]) * wo.w;
        }
    }
    float z0 = zp0 + __shfl_xor(zp0, 32);
    float z1 = zp1 + __shfl_xor(zp1, 32);

    // all 64 lanes: lo half handles rg0 row l31, hi half rg1 row l31
    {
        float z = hi ? z1 : z0;
        const float CC = 0.8975979010256552f;   // 2*pi/7
        float a = 0.f;
        #pragma unroll
        for (int k = 0; k < 32; ++k)
            a += sob[k] * sinf(CC * soa[k] * z);
        float mm  = expf(fabsf(a));
        float res = 4.f * z * mm / (4.f * mm + 5.f);
        out[n0 + 32 * hi + l31] = (a > 0.f) ? res : ((a < 0.f) ? -res : 0.f);
    }
}

extern "C" void kernel_launch(void* const* d_in, const int* in_sizes, int n_in,
                              void* d_out, int out_size, void* d_ws, size_t ws_size,
                              hipStream_t stream) {
    const float* x    = (const float*)d_in[0];
    const float* W1   = (const float*)d_in[1];
    const float* W2   = (const float*)d_in[2];
    const float* Wout = (const float*)d_in[3];
    const float* soa  = (const float*)d_in[8];
    const float* sob  = (const float*)d_in[9];
    float* outp = (float*)d_out;
    u16* ws = (u16*)d_ws;   // needs 294912 B

    hipLaunchKernelGGL(presplit, dim3(24), dim3(256), 0, stream, W1, W2, ws);
    hipLaunchKernelGGL(fused_mlp10, dim3(NROWS / 256), dim3(256), 0, stream,
                       x, ws, Wout, soa, sob, outp);
}

// Round 11
// 50.620 us; speedup vs baseline: 1.2320x; 1.2320x over previous
//
#include <hip/hip_runtime.h>
#include <math.h>

// Analytic collapse (verified R1-R10, absmax 3.9e-3):
//   t = tanh(W1 @ x_n); v = tanh(W2 @ t); z = Wout . v
//   a = sum_h sob[h]*sin(2*pi*soa[h]*z/7);  out = sign(a)*4*z*e^|a|/(4e^|a|+5)
//
// R11: identical fp32-emulated MFMA arithmetic (bf16 3-level split, 6 products
// per accumulator, same order -> bit-identical to R4-R10). Schedule only:
//   - NO setprio, NO sched_barrier: waves + compiler free to overlap pipes.
//   - pack(g+1) hand-interleaved between the ot-chains of cluster(g): each
//     wave's pack VALU hides under its own MFMA stream (ILP not TLP).
//   - 4-buffer A rotation (48 KB), staged 2 phases ahead, counted vmcnt
//     (8 steady / 6 transition / 3,0 tail) - never a mid-loop full drain.
//   - RACE FIX vs R9: vmcnt BEFORE s_barrier, so the barrier certifies all
//     waves' A(g) glds have landed before any wave reads A(g).
//   - 2 blocks/CU x 4 waves (grid 512, 256 thr).

typedef __bf16 bf16x8 __attribute__((ext_vector_type(8)));
typedef float  f32x16 __attribute__((ext_vector_type(16)));
typedef unsigned int u32;
typedef unsigned short u16;

union FRAG { uint4 q; bf16x8 v; };

#define NROWS 65536

#define WAITV(N) asm volatile("s_waitcnt vmcnt(" #N ")" ::: "memory")
#define BARRIER() asm volatile("s_barrier" ::: "memory")

// ---- bf16 3-level split: x = h + m + l + O(2^-25 |x|) ----
__device__ __forceinline__ void split3(float x, u32& h, u32& m, u32& l) {
    u32 u = __float_as_uint(x);
    h = u >> 16;
    float hf = __uint_as_float(u & 0xFFFF0000u);
    float r1 = x - hf;                       // exact
    u32 u1 = __float_as_uint(r1);
    m = u1 >> 16;
    float mf = __uint_as_float(u1 & 0xFFFF0000u);
    float r2 = r1 - mf;                      // exact
    u32 u2 = __float_as_uint(r2);
    l = (u2 + 0x7FFFu + ((u2 >> 16) & 1u)) >> 16;   // RNE
}

__device__ __forceinline__ void pack2(float a, float b, u32& H, u32& M, u32& L) {
    u32 h0, m0, l0, h1, m1, l1;
    split3(a, h0, m0, l0); split3(b, h1, m1, l1);
    H = h0 | (h1 << 16); M = m0 | (m1 << 16); L = l0 | (l1 << 16);
}

__device__ __forceinline__ float fast_tanh(float x) {
    float e = __expf(2.f * x);
    return 1.f - 2.f * __builtin_amdgcn_rcpf(e + 1.f);  // inf-safe, ~4e-7 abs err
}

__device__ __forceinline__ void glds16(const uint4* g, uint4* l) {
    __builtin_amdgcn_global_load_lds(
        (const __attribute__((address_space(1))) void*)g,
        (__attribute__((address_space(3))) void*)l, 16, 0, 0);
}

// ====== pre-kernel: split W1/W2 into fragment-major bf16 planes in d_ws ======
// uint4 units: L1 frag f=g*4+ot, levels at 0/4096/8192, idx=lv*4096+f*64+lane
//              L2 frag f2=s*4+ot, at 12288+lv*2048+f2*64+lane
__global__ void presplit(const float* __restrict__ W1,
                         const float* __restrict__ W2,
                         u16* __restrict__ ws)
{
    int t = blockIdx.x * 256 + threadIdx.x;   // 0..6143
    const float* src;
    size_t dbase, lstep;
    if (t < 4096) {
        int f = t >> 6, lane = t & 63;
        int c = f >> 4, s = (f >> 2) & 3, ot = f & 3;
        int l31 = lane & 31, hi = lane >> 5;
        src   = W1 + (size_t)(32 * ot + l31) * 256 + c * 64 + s * 16 + 8 * hi;
        dbase = (size_t)(f * 64 + lane) * 8;
        lstep = 32768;
    } else {
        int t2 = t - 4096;
        int f = t2 >> 6, lane = t2 & 63;
        int s = f >> 2, ot = f & 3;
        int l31 = lane & 31, hi = lane >> 5;
        src   = W2 + (size_t)(32 * ot + l31) * 128 + s * 16 + 8 * hi;
        dbase = 98304 + (size_t)(f * 64 + lane) * 8;
        lstep = 16384;
    }
    u16 H[8], M[8], L[8];
    #pragma unroll
    for (int j = 0; j < 8; ++j) {
        u32 h, m, l;
        split3(src[j], h, m, l);
        H[j] = (u16)h; M[j] = (u16)m; L[j] = (u16)l;
    }
    #pragma unroll
    for (int j = 0; j < 8; ++j) {
        ws[dbase + j]             = H[j];
        ws[dbase + lstep + j]     = M[j];
        ws[dbase + 2 * lstep + j] = L[j];
    }
}

// ================= main kernel ==============================================
// 256 thr = 4 waves; 128 rows/block; wave w owns rows 32w..32w+31; grid = 512.
__global__ __launch_bounds__(256, 2)
void fused_mlp11(const float* __restrict__ x,
                 const u16*   __restrict__ wsp,
                 const float* __restrict__ Wout,
                 const float* __restrict__ soa,
                 const float* __restrict__ sob,
                 float* __restrict__ out)
{
    __shared__ uint4 Ab[4][768];              // 48 KB: 4-deep A-batch rotation

    const int tid  = threadIdx.x;
    const int w    = tid >> 6;                // 0..3
    const int lane = tid & 63;
    const int l31  = lane & 31;
    const int hi   = lane >> 5;
    const int nloc = (w << 5) + l31;          // this lane's local row
    const int n0g  = blockIdx.x * 128;

    const uint4*  wf   = reinterpret_cast<const uint4*>(wsp);
    const float4* xrow = reinterpret_cast<const float4*>(x) + (size_t)(n0g + nloc) * 64;

    // wave w stages items i = 3w..3w+2 (of 12) of K16-step g's A-batch
    auto stage = [&](int g, uint4* dst) {
        #pragma unroll
        for (int j = 0; j < 3; ++j) {
            int i  = w * 3 + j;               // 0..11
            int lv = i >> 2, ot = i & 3;
            const uint4* src = (g < 16)
                ? wf + lv * 4096 + (g * 4 + ot) * 64 + lane
                : wf + 12288 + lv * 2048 + ((g - 16) * 4 + ot) * 64 + lane;
            glds16(src, dst + i * 64);
        }
    };
    auto issueX = [&](int g, float4& a, float4& b) {
        a = xrow[g * 4 + hi * 2];
        b = xrow[g * 4 + hi * 2 + 1];
    };

    f32x16 acc[4];
    #pragma unroll
    for (int ot = 0; ot < 4; ++ot) acc[ot] = (f32x16)0.f;

    // one K16-step: 4 ot-chains of 6 MFMAs; one pack2 of NEXT phase's B
    // interleaved after each chain (per-acc product order unchanged).
    auto clusterP = [&](const uint4* Ac, f32x16* A,
                        const FRAG& Bh, const FRAG& Bm, const FRAG& Bl,
                        const float4& nx0, const float4& nx1,
                        FRAG& NH, FRAG& NM, FRAG& NL, bool dopack) {
        #pragma unroll
        for (int ot = 0; ot < 4; ++ot) {
            FRAG Ah, Am, Al;
            Ah.q = Ac[ot * 64 + lane];
            Am.q = Ac[(4 + ot) * 64 + lane];
            Al.q = Ac[(8 + ot) * 64 + lane];
            A[ot] = __builtin_amdgcn_mfma_f32_32x32x16_bf16(Ah.v, Bh.v, A[ot], 0,0,0);
            A[ot] = __builtin_amdgcn_mfma_f32_32x32x16_bf16(Ah.v, Bm.v, A[ot], 0,0,0);
            A[ot] = __builtin_amdgcn_mfma_f32_32x32x16_bf16(Am.v, Bh.v, A[ot], 0,0,0);
            A[ot] = __builtin_amdgcn_mfma_f32_32x32x16_bf16(Am.v, Bm.v, A[ot], 0,0,0);
            A[ot] = __builtin_amdgcn_mfma_f32_32x32x16_bf16(Ah.v, Bl.v, A[ot], 0,0,0);
            A[ot] = __builtin_amdgcn_mfma_f32_32x32x16_bf16(Al.v, Bh.v, A[ot], 0,0,0);
            if (dopack) {
                switch (ot) {   // folds after unroll (static indices)
                    case 0: pack2(nx0.x, nx0.y, NH.q.x, NM.q.x, NL.q.x); break;
                    case 1: pack2(nx0.z, nx0.w, NH.q.y, NM.q.y, NL.q.y); break;
                    case 2: pack2(nx1.x, nx1.y, NH.q.z, NM.q.z, NL.q.z); break;
                    case 3: pack2(nx1.z, nx1.w, NH.q.w, NM.q.w, NL.q.w); break;
                }
            }
        }
    };

    FRAG Bevh, Bevm, Bevl, Bodh, Bodm, Bodl;
    float4 x0a, x0b, x1a, x1b, x2a, x2b, x3a, x3b;

    // ---- prologue: x(0),A(0),x(1),A(1); pack B(0) ----
    issueX(0, x0a, x0b);
    stage(0, Ab[0]);
    issueX(1, x1a, x1b);
    stage(1, Ab[1]);
    WAITV(8);                                 // x(0) landed
    pack2(x0a.x, x0a.y, Bevh.q.x, Bevm.q.x, Bevl.q.x);
    pack2(x0a.z, x0a.w, Bevh.q.y, Bevm.q.y, Bevl.q.y);
    pack2(x0b.x, x0b.y, Bevh.q.z, Bevm.q.z, Bevl.q.z);
    pack2(x0b.z, x0b.w, Bevh.q.w, Bevm.q.w, Bevl.q.w);

    // =================== layer 1 phases 0..11 (3 x 4 phases) =================
    #pragma unroll 1
    for (int i = 0; i < 3; ++i) {
        int g0 = 4 * i;
        // phase g0+0: reads Ab[0], packs B(g0+1)
        issueX(g0 + 2, x2a, x2b); stage(g0 + 2, Ab[2]);
        WAITV(8); BARRIER();
        clusterP(Ab[0], acc, Bevh, Bevm, Bevl, x1a, x1b, Bodh, Bodm, Bodl, true);
        // phase g0+1: reads Ab[1]
        issueX(g0 + 3, x3a, x3b); stage(g0 + 3, Ab[3]);
        WAITV(8); BARRIER();
        clusterP(Ab[1], acc, Bodh, Bodm, Bodl, x2a, x2b, Bevh, Bevm, Bevl, true);
        // phase g0+2: reads Ab[2]
        issueX(g0 + 4, x0a, x0b); stage(g0 + 4, Ab[0]);
        WAITV(8); BARRIER();
        clusterP(Ab[2], acc, Bevh, Bevm, Bevl, x3a, x3b, Bodh, Bodm, Bodl, true);
        // phase g0+3: reads Ab[3]
        issueX(g0 + 5, x1a, x1b); stage(g0 + 5, Ab[1]);
        WAITV(8); BARRIER();
        clusterP(Ab[3], acc, Bodh, Bodm, Bodl, x0a, x0b, Bevh, Bevm, Bevl, true);
    }

    // ---- phases 12..15 (x issues end at step 15) ----
    issueX(14, x2a, x2b); stage(14, Ab[2]);
    WAITV(8); BARRIER();
    clusterP(Ab[0], acc, Bevh, Bevm, Bevl, x1a, x1b, Bodh, Bodm, Bodl, true);

    issueX(15, x3a, x3b); stage(15, Ab[3]);
    WAITV(8); BARRIER();
    clusterP(Ab[1], acc, Bodh, Bodm, Bodl, x2a, x2b, Bevh, Bevm, Bevl, true);

    stage(16, Ab[0]);
    WAITV(6); BARRIER();
    clusterP(Ab[2], acc, Bevh, Bevm, Bevl, x3a, x3b, Bodh, Bodm, Bodl, true);

    stage(17, Ab[1]);
    WAITV(6); BARRIER();
    clusterP(Ab[3], acc, Bodh, Bodm, Bodl, x0a, x0b, Bevh, Bevm, Bevl, false);

    // ====== t = tanh(D1); build layer-2 B-frags in registers (3 planes) ======
    // (A(16),A(17) glds in flight land under this VALU block)
    FRAG tf[3][8];
    #pragma unroll
    for (int ft = 0; ft < 4; ++ft) {
        #pragma unroll
        for (int sub = 0; sub < 2; ++sub) {
            int s = 2 * ft + sub;
            float tv[8];
            u32 th[8], tm[8], tlv[8];
            #pragma unroll
            for (int j = 0; j < 8; ++j) {
                tv[j] = fast_tanh(acc[ft][8 * sub + j]);
                split3(tv[j], th[j], tm[j], tlv[j]);
            }
            #pragma unroll
            for (int lv = 0; lv < 3; ++lv) {
                const u32* t_ = (lv == 0) ? th : (lv == 1) ? tm : tlv;
                u32 P0 = t_[0] | (t_[1] << 16);
                u32 P1 = t_[2] | (t_[3] << 16);
                u32 Q0 = t_[4] | (t_[5] << 16);
                u32 Q1 = t_[6] | (t_[7] << 16);
                u32 sP0 = (u32)__shfl_xor((int)P0, 32);
                u32 sP1 = (u32)__shfl_xor((int)P1, 32);
                u32 sQ0 = (u32)__shfl_xor((int)Q0, 32);
                u32 sQ1 = (u32)__shfl_xor((int)Q1, 32);
                tf[lv][s].q.x = hi ? sQ0 : P0;
                tf[lv][s].q.y = hi ? sQ1 : P1;
                tf[lv][s].q.z = hi ? Q0 : sP0;
                tf[lv][s].q.w = hi ? Q1 : sP1;
            }
        }
    }

    // =================== layer 2: phases 16..23 ==============================
    f32x16 acc2[4];
    #pragma unroll
    for (int ot = 0; ot < 4; ++ot) acc2[ot] = (f32x16)0.f;

    float4 dm0, dm1;   // dummy (unused, dopack=false)
    FRAG dF0, dF1, dF2;

    stage(18, Ab[2]); WAITV(6); BARRIER();
    clusterP(Ab[0], acc2, tf[0][0], tf[1][0], tf[2][0], dm0, dm1, dF0, dF1, dF2, false);
    stage(19, Ab[3]); WAITV(6); BARRIER();
    clusterP(Ab[1], acc2, tf[0][1], tf[1][1], tf[2][1], dm0, dm1, dF0, dF1, dF2, false);
    stage(20, Ab[0]); WAITV(6); BARRIER();
    clusterP(Ab[2], acc2, tf[0][2], tf[1][2], tf[2][2], dm0, dm1, dF0, dF1, dF2, false);
    stage(21, Ab[1]); WAITV(6); BARRIER();
    clusterP(Ab[3], acc2, tf[0][3], tf[1][3], tf[2][3], dm0, dm1, dF0, dF1, dF2, false);
    stage(22, Ab[2]); WAITV(6); BARRIER();
    clusterP(Ab[0], acc2, tf[0][4], tf[1][4], tf[2][4], dm0, dm1, dF0, dF1, dF2, false);
    stage(23, Ab[3]); WAITV(6); BARRIER();
    clusterP(Ab[1], acc2, tf[0][5], tf[1][5], tf[2][5], dm0, dm1, dF0, dF1, dF2, false);
    WAITV(3); BARRIER();
    clusterP(Ab[2], acc2, tf[0][6], tf[1][6], tf[2][6], dm0, dm1, dF0, dF1, dF2, false);
    WAITV(0); BARRIER();
    clusterP(Ab[3], acc2, tf[0][7], tf[1][7], tf[2][7], dm0, dm1, dF0, dF1, dF2, false);

    // ====== epilogue: v = tanh(D2); z = Wout . v ; analytic tail ======
    float zp = 0.f;
    #pragma unroll
    for (int ft = 0; ft < 4; ++ft) {
        #pragma unroll
        for (int rg = 0; rg < 4; ++rg) {
            const float4 wo = *reinterpret_cast<const float4*>(Wout + 32 * ft + 8 * rg + 4 * hi);
            zp += fast_tanh(acc2[ft][4 * rg + 0]) * wo.x
                + fast_tanh(acc2[ft][4 * rg + 1]) * wo.y
                + fast_tanh(acc2[ft][4 * rg + 2]) * wo.z
                + fast_tanh(acc2[ft][4 * rg + 3]) * wo.w;
        }
    }
    float z = zp + __shfl_xor(zp, 32);

    if (lane < 32) {
        const float CC = 0.8975979010256552f;   // 2*pi/7
        float a = 0.f;
        #pragma unroll
        for (int k = 0; k < 32; ++k)
            a += sob[k] * sinf(CC * soa[k] * z);
        float mm  = expf(fabsf(a));
        float res = 4.f * z * mm / (4.f * mm + 5.f);
        out[n0g + (w << 5) + lane] = (a > 0.f) ? res : ((a < 0.f) ? -res : 0.f);
    }
}

extern "C" void kernel_launch(void* const* d_in, const int* in_sizes, int n_in,
                              void* d_out, int out_size, void* d_ws, size_t ws_size,
                              hipStream_t stream) {
    const float* x    = (const float*)d_in[0];
    const float* W1   = (const float*)d_in[1];
    const float* W2   = (const float*)d_in[2];
    const float* Wout = (const float*)d_in[3];
    const float* soa  = (const float*)d_in[8];
    const float* sob  = (const float*)d_in[9];
    float* outp = (float*)d_out;
    u16* ws = (u16*)d_ws;   // needs 294912 B

    hipLaunchKernelGGL(presplit, dim3(24), dim3(256), 0, stream, W1, W2, ws);
    hipLaunchKernelGGL(fused_mlp11, dim3(NROWS / 128), dim3(256), 0, stream,
                       x, ws, Wout, soa, sob, outp);
}

// Round 12
// 49.586 us; speedup vs baseline: 1.2577x; 1.0208x over previous
//
#include <hip/hip_runtime.h>
#include <math.h>

// Analytic collapse (verified R1-R11, absmax 3.9e-3):
//   t = tanh(W1 @ x_n); v = tanh(W2 @ t); z = Wout . v
//   a = sum_h sob[h]*sin(2*pi*soa[h]*z/7);  out = sign(a)*4*z*e^|a|/(4e^|a|+5)
//
// R12: identical fp32-emulated MFMA arithmetic (bf16 3-level split, 6 products
// per accumulator, same order -> bit-identical to R4-R11). Key change:
//   A-fragments (Ah,Am) for step g+1 are ds_read into a REGISTER ping-pong
//   during step g's MFMA cluster -> the cluster consumes registers only; the
//   lgkmcnt wait moves off the critical path. Al is read at cluster head
//   (first use ~5 MFMAs later, latency self-covered) to save 32 VGPR.
//   tf l-plane in wave-private LDS. DMA 2-ahead in 4-deep rotation with
//   counted vmcnt (5 steady / 3 tail / 0 last); vmcnt BEFORE s_barrier.
//   No setprio, no sched_barrier. 2 blocks/CU x 4 waves (grid 512).

typedef __bf16 bf16x8 __attribute__((ext_vector_type(8)));
typedef float  f32x16 __attribute__((ext_vector_type(16)));
typedef unsigned int u32;
typedef unsigned short u16;

union FRAG { uint4 q; bf16x8 v; };

#define NROWS 65536

#define WAITV(N) asm volatile("s_waitcnt vmcnt(" #N ")" ::: "memory")
#define BARRIER() asm volatile("s_barrier" ::: "memory")

// ---- bf16 3-level split: x = h + m + l + O(2^-25 |x|) ----
__device__ __forceinline__ void split3(float x, u32& h, u32& m, u32& l) {
    u32 u = __float_as_uint(x);
    h = u >> 16;
    float hf = __uint_as_float(u & 0xFFFF0000u);
    float r1 = x - hf;                       // exact
    u32 u1 = __float_as_uint(r1);
    m = u1 >> 16;
    float mf = __uint_as_float(u1 & 0xFFFF0000u);
    float r2 = r1 - mf;                      // exact
    u32 u2 = __float_as_uint(r2);
    l = (u2 + 0x7FFFu + ((u2 >> 16) & 1u)) >> 16;   // RNE
}

__device__ __forceinline__ void pack2(float a, float b, u32& H, u32& M, u32& L) {
    u32 h0, m0, l0, h1, m1, l1;
    split3(a, h0, m0, l0); split3(b, h1, m1, l1);
    H = h0 | (h1 << 16); M = m0 | (m1 << 16); L = l0 | (l1 << 16);
}

__device__ __forceinline__ float fast_tanh(float x) {
    float e = __expf(2.f * x);
    return 1.f - 2.f * __builtin_amdgcn_rcpf(e + 1.f);  // inf-safe, ~4e-7 abs err
}

__device__ __forceinline__ void glds16(const uint4* g, uint4* l) {
    __builtin_amdgcn_global_load_lds(
        (const __attribute__((address_space(1))) void*)g,
        (__attribute__((address_space(3))) void*)l, 16, 0, 0);
}

// ====== pre-kernel: split W1/W2 into fragment-major bf16 planes in d_ws ======
// uint4 units: L1 frag f=g*4+ot, levels at 0/4096/8192, idx=lv*4096+f*64+lane
//              L2 frag f2=s*4+ot, at 12288+lv*2048+f2*64+lane
__global__ void presplit(const float* __restrict__ W1,
                         const float* __restrict__ W2,
                         u16* __restrict__ ws)
{
    int t = blockIdx.x * 256 + threadIdx.x;   // 0..6143
    const float* src;
    size_t dbase, lstep;
    if (t < 4096) {
        int f = t >> 6, lane = t & 63;
        int c = f >> 4, s = (f >> 2) & 3, ot = f & 3;
        int l31 = lane & 31, hi = lane >> 5;
        src   = W1 + (size_t)(32 * ot + l31) * 256 + c * 64 + s * 16 + 8 * hi;
        dbase = (size_t)(f * 64 + lane) * 8;
        lstep = 32768;
    } else {
        int t2 = t - 4096;
        int f = t2 >> 6, lane = t2 & 63;
        int s = f >> 2, ot = f & 3;
        int l31 = lane & 31, hi = lane >> 5;
        src   = W2 + (size_t)(32 * ot + l31) * 128 + s * 16 + 8 * hi;
        dbase = 98304 + (size_t)(f * 64 + lane) * 8;
        lstep = 16384;
    }
    u16 H[8], M[8], L[8];
    #pragma unroll
    for (int j = 0; j < 8; ++j) {
        u32 h, m, l;
        split3(src[j], h, m, l);
        H[j] = (u16)h; M[j] = (u16)m; L[j] = (u16)l;
    }
    #pragma unroll
    for (int j = 0; j < 8; ++j) {
        ws[dbase + j]             = H[j];
        ws[dbase + lstep + j]     = M[j];
        ws[dbase + 2 * lstep + j] = L[j];
    }
}

// ================= main kernel ==============================================
// 256 thr = 4 waves; 128 rows/block; wave w owns rows 32w..32w+31; grid = 512.
__global__ __launch_bounds__(256, 2)
void fused_mlp12(const float* __restrict__ x,
                 const u16*   __restrict__ wsp,
                 const float* __restrict__ Wout,
                 const float* __restrict__ soa,
                 const float* __restrict__ sob,
                 float* __restrict__ out)
{
    __shared__ uint4 Ab[4][768];              // 48 KB: 4-deep A-batch rotation
    __shared__ uint4 tl[2048];                // 32 KB: tf l-plane [w][s][lane]

    const int tid  = threadIdx.x;
    const int w    = tid >> 6;                // 0..3
    const int lane = tid & 63;
    const int l31  = lane & 31;
    const int hi   = lane >> 5;
    const int nloc = (w << 5) + l31;          // this lane's local row
    const int n0g  = blockIdx.x * 128;

    const uint4*  wf   = reinterpret_cast<const uint4*>(wsp);
    const float4* xrow = reinterpret_cast<const float4*>(x) + (size_t)(n0g + nloc) * 64;

    // wave w stages items i = 3w..3w+2 (of 12) of K16-step g's A-batch
    auto stage = [&](int g, uint4* dst) {
        #pragma unroll
        for (int j = 0; j < 3; ++j) {
            int i  = w * 3 + j;               // 0..11
            int lv = i >> 2, ot = i & 3;
            const uint4* src = (g < 16)
                ? wf + lv * 4096 + (g * 4 + ot) * 64 + lane
                : wf + 12288 + lv * 2048 + ((g - 16) * 4 + ot) * 64 + lane;
            glds16(src, dst + i * 64);
        }
    };

    f32x16 acc[4];
    #pragma unroll
    for (int ot = 0; ot < 4; ++ot) acc[ot] = (f32x16)0.f;

    FRAG RAa[8], RAb[8];                      // A-frag register ping-pong (Ah,Am)
    FRAG Bevh, Bevm, Bevl, Bodh, Bodm, Bodl;
    float4 x0a, x0b, x1a, x1b, x2a, x2b, x3a, x3b;

    auto readA8 = [&](const uint4* buf, FRAG* R) {
        #pragma unroll
        for (int i = 0; i < 8; ++i) R[i].q = buf[i * 64 + lane];
    };
    auto packB = [&](const float4& a, const float4& b, FRAG& Bh, FRAG& Bm, FRAG& Bl) {
        pack2(a.x, a.y, Bh.q.x, Bm.q.x, Bl.q.x);
        pack2(a.z, a.w, Bh.q.y, Bm.q.y, Bl.q.y);
        pack2(b.x, b.y, Bh.q.z, Bm.q.z, Bl.q.z);
        pack2(b.z, b.w, Bh.q.w, Bm.q.w, Bl.q.w);
    };
    // 24-MFMA cluster: Ah,Am from regs R; Al read at head (first use ~5 MFMAs
    // later). Per-accumulator product order identical to R4-R11.
    auto cluster = [&](const uint4* Ac, FRAG* R, f32x16* A,
                       const FRAG& Bh, const FRAG& Bm, const FRAG& Bl) {
        FRAG Al[4];
        #pragma unroll
        for (int ot = 0; ot < 4; ++ot) Al[ot].q = Ac[(8 + ot) * 64 + lane];
        #pragma unroll
        for (int ot = 0; ot < 4; ++ot) {
            A[ot] = __builtin_amdgcn_mfma_f32_32x32x16_bf16(R[ot].v,     Bh.v, A[ot], 0,0,0);
            A[ot] = __builtin_amdgcn_mfma_f32_32x32x16_bf16(R[ot].v,     Bm.v, A[ot], 0,0,0);
            A[ot] = __builtin_amdgcn_mfma_f32_32x32x16_bf16(R[4 + ot].v, Bh.v, A[ot], 0,0,0);
            A[ot] = __builtin_amdgcn_mfma_f32_32x32x16_bf16(R[4 + ot].v, Bm.v, A[ot], 0,0,0);
            A[ot] = __builtin_amdgcn_mfma_f32_32x32x16_bf16(R[ot].v,     Bl.v, A[ot], 0,0,0);
            A[ot] = __builtin_amdgcn_mfma_f32_32x32x16_bf16(Al[ot].v,    Bh.v, A[ot], 0,0,0);
        }
    };

    // ---- prologue: batches 0,1 staged; x(0),x(1) issued; A(0)->RAa; B(0) ----
    stage(0, Ab[0]);
    x0a = xrow[hi * 2]; x0b = xrow[hi * 2 + 1];
    stage(1, Ab[1]);
    x1a = xrow[4 + hi * 2]; x1b = xrow[4 + hi * 2 + 1];
    WAITV(5);            // batch 0 + x(0) landed (stage(1)+x(1) stay in flight)
    BARRIER();
    readA8(Ab[0], RAa);
    packB(x0a, x0b, Bevh, Bevm, Bevl);

    // =================== layer 1 phases 0..11 (4-phase body) =================
    #pragma unroll 1
    for (int i = 0; i < 3; ++i) {
        int P = 4 * i;
        // phase P+0: MFMA step P (regs RAa, B ev); prefetch A(P+1)->RAb
        stage(P + 2, Ab[2]);
        { int g = P + 2; x2a = xrow[g * 4 + hi * 2]; x2b = xrow[g * 4 + hi * 2 + 1]; }
        WAITV(5); BARRIER();
        readA8(Ab[1], RAb);
        packB(x1a, x1b, Bodh, Bodm, Bodl);
        cluster(Ab[0], RAa, acc, Bevh, Bevm, Bevl);
        // phase P+1
        stage(P + 3, Ab[3]);
        { int g = P + 3; x3a = xrow[g * 4 + hi * 2]; x3b = xrow[g * 4 + hi * 2 + 1]; }
        WAITV(5); BARRIER();
        readA8(Ab[2], RAa);
        packB(x2a, x2b, Bevh, Bevm, Bevl);
        cluster(Ab[1], RAb, acc, Bodh, Bodm, Bodl);
        // phase P+2
        stage(P + 4, Ab[0]);
        { int g = P + 4; x0a = xrow[g * 4 + hi * 2]; x0b = xrow[g * 4 + hi * 2 + 1]; }
        WAITV(5); BARRIER();
        readA8(Ab[3], RAb);
        packB(x3a, x3b, Bodh, Bodm, Bodl);
        cluster(Ab[2], RAa, acc, Bevh, Bevm, Bevl);
        // phase P+3
        stage(P + 5, Ab[1]);
        { int g = P + 5; x1a = xrow[g * 4 + hi * 2]; x1b = xrow[g * 4 + hi * 2 + 1]; }
        WAITV(5); BARRIER();
        readA8(Ab[0], RAa);
        packB(x0a, x0b, Bevh, Bevm, Bevl);
        cluster(Ab[3], RAb, acc, Bodh, Bodm, Bodl);
    }

    // ---- phases 12..15 ----
    stage(14, Ab[2]);
    x2a = xrow[56 + hi * 2]; x2b = xrow[56 + hi * 2 + 1];
    WAITV(5); BARRIER();
    readA8(Ab[1], RAb);
    packB(x1a, x1b, Bodh, Bodm, Bodl);
    cluster(Ab[0], RAa, acc, Bevh, Bevm, Bevl);      // step 12

    stage(15, Ab[3]);
    x3a = xrow[60 + hi * 2]; x3b = xrow[60 + hi * 2 + 1];
    WAITV(5); BARRIER();
    readA8(Ab[2], RAa);
    packB(x2a, x2b, Bevh, Bevm, Bevl);
    cluster(Ab[1], RAb, acc, Bodh, Bodm, Bodl);      // step 13

    stage(16, Ab[0]);
    WAITV(3); BARRIER();
    readA8(Ab[3], RAb);
    packB(x3a, x3b, Bodh, Bodm, Bodl);
    cluster(Ab[2], RAa, acc, Bevh, Bevm, Bevl);      // step 14

    stage(17, Ab[1]);
    WAITV(3); BARRIER();
    readA8(Ab[0], RAa);                              // A(16) -> regs
    cluster(Ab[3], RAb, acc, Bodh, Bodm, Bodl);      // step 15

    // ====== t = tanh(D1); tf h,m in regs; l-plane -> wave-private LDS ======
    FRAG tfh[8], tfm[8];
    #pragma unroll
    for (int ft = 0; ft < 4; ++ft) {
        #pragma unroll
        for (int sub = 0; sub < 2; ++sub) {
            int s = 2 * ft + sub;
            float tv[8];
            u32 th[8], tm[8], tlv[8];
            #pragma unroll
            for (int j = 0; j < 8; ++j) {
                tv[j] = fast_tanh(acc[ft][8 * sub + j]);
                split3(tv[j], th[j], tm[j], tlv[j]);
            }
            #pragma unroll
            for (int lv = 0; lv < 3; ++lv) {
                const u32* t_ = (lv == 0) ? th : (lv == 1) ? tm : tlv;
                u32 P0 = t_[0] | (t_[1] << 16);
                u32 P1 = t_[2] | (t_[3] << 16);
                u32 Q0 = t_[4] | (t_[5] << 16);
                u32 Q1 = t_[6] | (t_[7] << 16);
                u32 sP0 = (u32)__shfl_xor((int)P0, 32);
                u32 sP1 = (u32)__shfl_xor((int)P1, 32);
                u32 sQ0 = (u32)__shfl_xor((int)Q0, 32);
                u32 sQ1 = (u32)__shfl_xor((int)Q1, 32);
                uint4 q;
                q.x = hi ? sQ0 : P0;
                q.y = hi ? sQ1 : P1;
                q.z = hi ? Q0 : sP0;
                q.w = hi ? Q1 : sP1;
                if (lv == 0)      tfh[s].q = q;
                else if (lv == 1) tfm[s].q = q;
                else              tl[(w << 9) + (s << 6) + lane] = q;   // in-order DS
            }
        }
    }

    // =================== layer 2: phases 16..23 ==============================
    f32x16 acc2[4];
    #pragma unroll
    for (int ot = 0; ot < 4; ++ot) acc2[ot] = (f32x16)0.f;

    FRAG Blev, Blod;
    Blev.q = tl[(w << 9) + lane];                    // l(0)

    stage(18, Ab[2]); WAITV(3); BARRIER();
    readA8(Ab[1], RAb); Blod.q = tl[(w << 9) + (1 << 6) + lane];
    cluster(Ab[0], RAa, acc2, tfh[0], tfm[0], Blev);   // s=0

    stage(19, Ab[3]); WAITV(3); BARRIER();
    readA8(Ab[2], RAa); Blev.q = tl[(w << 9) + (2 << 6) + lane];
    cluster(Ab[1], RAb, acc2, tfh[1], tfm[1], Blod);   // s=1

    stage(20, Ab[0]); WAITV(3); BARRIER();
    readA8(Ab[3], RAb); Blod.q = tl[(w << 9) + (3 << 6) + lane];
    cluster(Ab[2], RAa, acc2, tfh[2], tfm[2], Blev);   // s=2

    stage(21, Ab[1]); WAITV(3); BARRIER();
    readA8(Ab[0], RAa); Blev.q = tl[(w << 9) + (4 << 6) + lane];
    cluster(Ab[3], RAb, acc2, tfh[3], tfm[3], Blod);   // s=3

    stage(22, Ab[2]); WAITV(3); BARRIER();
    readA8(Ab[1], RAb); Blod.q = tl[(w << 9) + (5 << 6) + lane];
    cluster(Ab[0], RAa, acc2, tfh[4], tfm[4], Blev);   // s=4

    stage(23, Ab[3]); WAITV(3); BARRIER();
    readA8(Ab[2], RAa); Blev.q = tl[(w << 9) + (6 << 6) + lane];
    cluster(Ab[1], RAb, acc2, tfh[5], tfm[5], Blod);   // s=5

    WAITV(0); BARRIER();
    readA8(Ab[3], RAb); Blod.q = tl[(w << 9) + (7 << 6) + lane];
    cluster(Ab[2], RAa, acc2, tfh[6], tfm[6], Blev);   // s=6

    cluster(Ab[3], RAb, acc2, tfh[7], tfm[7], Blod);   // s=7

    // ====== epilogue: v = tanh(D2); z = Wout . v ; analytic tail ======
    float zp = 0.f;
    #pragma unroll
    for (int ft = 0; ft < 4; ++ft) {
        #pragma unroll
        for (int rg = 0; rg < 4; ++rg) {
            const float4 wo = *reinterpret_cast<const float4*>(Wout + 32 * ft + 8 * rg + 4 * hi);
            zp += fast_tanh(acc2[ft][4 * rg + 0]) * wo.x
                + fast_tanh(acc2[ft][4 * rg + 1]) * wo.y
                + fast_tanh(acc2[ft][4 * rg + 2]) * wo.z
                + fast_tanh(acc2[ft][4 * rg + 3]) * wo.w;
        }
    }
    float z = zp + __shfl_xor(zp, 32);

    if (lane < 32) {
        const float CC = 0.8975979010256552f;   // 2*pi/7
        float a = 0.f;
        #pragma unroll
        for (int k = 0; k < 32; ++k)
            a += sob[k] * sinf(CC * soa[k] * z);
        float mm  = expf(fabsf(a));
        float res = 4.f * z * mm / (4.f * mm + 5.f);
        out[n0g + (w << 5) + lane] = (a > 0.f) ? res : ((a < 0.f) ? -res : 0.f);
    }
}

extern "C" void kernel_launch(void* const* d_in, const int* in_sizes, int n_in,
                              void* d_out, int out_size, void* d_ws, size_t ws_size,
                              hipStream_t stream) {
    const float* x    = (const float*)d_in[0];
    const float* W1   = (const float*)d_in[1];
    const float* W2   = (const float*)d_in[2];
    const float* Wout = (const float*)d_in[3];
    const float* soa  = (const float*)d_in[8];
    const float* sob  = (const float*)d_in[9];
    float* outp = (float*)d_out;
    u16* ws = (u16*)d_ws;   // needs 294912 B

    hipLaunchKernelGGL(presplit, dim3(24), dim3(256), 0, stream, W1, W2, ws);
    hipLaunchKernelGGL(fused_mlp12, dim3(NROWS / 128), dim3(256), 0, stream,
                       x, ws, Wout, soa, sob, outp);
}